// Round 4
// baseline (11203.682 us; speedup 1.0000x reference)
//
#include <hip/hip_runtime.h>

typedef _Float16 half8 __attribute__((ext_vector_type(8)));
typedef float f32x4 __attribute__((ext_vector_type(4)));

#define Bb 256
#define Tt 512
#define NF 64
#define H1u 256
#define H2u 128
#define NGRP 16
#define Bs 16
#define NTHR 1024

#define NF1 10   // L1 k-frags (K=320)
#define NF2 12   // L2 k-frags (K=384)
#define NT1 4    // L1 16x16 tiles per wave
#define NT2 2    // L2 tiles per wave

// ws byte offsets
#define OFFB_WF1 0                       // [w16][tt4][f10][lane64] x half8
#define SZB_WF1  (16*4*10*64*16)         // 655360
#define OFFB_WF2 (OFFB_WF1+SZB_WF1)      // [w16][tt2][f12][lane64] x half8
#define SZB_WF2  (16*2*12*64*16)         // 393216
#define OFFB_BF1 (OFFB_WF2+SZB_WF2)      // [w16][tt4][lg4][4] f32
#define SZB_BF1  (16*4*4*4*4)            // 4096
#define OFFB_BF2 (OFFB_BF1+SZB_BF1)      // [w16][tt2][lg4][4] f32
#define SZB_BF2  (16*2*4*4*4)            // 2048

__device__ __forceinline__ float sigf(float x) {
    return 1.0f / (1.0f + __expf(-x));
}
__device__ __forceinline__ float tanhfast(float x) {
    return 2.0f / (1.0f + __expf(-2.0f * x)) - 1.0f;
}

// ---------------- prep: weights -> MFMA A-fragments (fp16) ----------------
__global__ __launch_bounds__(256) void prep4(
    const float* __restrict__ Wih1, const float* __restrict__ Whh1,
    const float* __restrict__ bih1, const float* __restrict__ bhh1,
    const float* __restrict__ Wih2, const float* __restrict__ Whh2,
    const float* __restrict__ bih2, const float* __restrict__ bhh2,
    char* __restrict__ wsb)
{
    _Float16* wf1 = (_Float16*)(wsb + OFFB_WF1);
    _Float16* wf2 = (_Float16*)(wsb + OFFB_WF2);
    float*    bf1 = (float*)(wsb + OFFB_BF1);
    float*    bf2 = (float*)(wsb + OFFB_BF2);
    const int stride = gridDim.x * blockDim.x;
    const int i0 = blockIdx.x * blockDim.x + threadIdx.x;

    // A-frag slot (lane,e): m = lane&15 (row in tile, r = uoff*4+gate),
    // k = f*32 + (lane>>4)*8 + e  (same k-convention used for B in-kernel)
    for (int idx = i0; idx < 16*4*NF1*64; idx += stride) {
        const int lane = idx & 63;
        int q = idx >> 6;
        const int f = q % NF1;  q /= NF1;
        const int tt = q & 3;
        const int w  = q >> 2;
        const int r = lane & 15;
        const int unit = w*16 + tt*4 + (r >> 2);
        const int gate = r & 3;
        const int grow = gate * H1u + unit;
        _Float16* dst = wf1 + (size_t)idx * 8;
        #pragma unroll
        for (int e = 0; e < 8; ++e) {
            const int k = f*32 + (lane >> 4)*8 + e;
            const float v = (k < NF) ? Wih1[grow*NF + k]
                                     : Whh1[grow*H1u + (k - NF)];
            dst[e] = (_Float16)v;
        }
    }
    for (int idx = i0; idx < 16*2*NF2*64; idx += stride) {
        const int lane = idx & 63;
        int q = idx >> 6;
        const int f = q % NF2;  q /= NF2;
        const int tt = q & 1;
        const int w  = q >> 1;
        const int r = lane & 15;
        const int unit = w*8 + tt*4 + (r >> 2);
        const int gate = r & 3;
        const int grow = gate * H2u + unit;
        _Float16* dst = wf2 + (size_t)idx * 8;
        #pragma unroll
        for (int e = 0; e < 8; ++e) {
            const int k = f*32 + (lane >> 4)*8 + e;
            const float v = (k < H1u) ? Wih2[grow*H1u + k]
                                      : Whh2[grow*H2u + (k - H1u)];
            dst[e] = (_Float16)v;
        }
    }
    // biases: lane's C-regs are gates 0..3 of unit (w,tt,lg=lane>>4)
    for (int idx = i0; idx < 16*4*4*4; idx += stride) {
        const int reg = idx & 3, lg = (idx >> 2) & 3;
        const int tt = (idx >> 4) & 3, w = idx >> 6;
        const int unit = w*16 + tt*4 + lg;
        const int grow = reg * H1u + unit;
        bf1[idx] = bih1[grow] + bhh1[grow];
    }
    for (int idx = i0; idx < 16*2*4*4; idx += stride) {
        const int reg = idx & 3, lg = (idx >> 2) & 3;
        const int tt = (idx >> 4) & 1, w = idx >> 5;
        const int unit = w*8 + tt*4 + lg;
        const int grow = reg * H2u + unit;
        bf2[idx] = bih2[grow] + bhh2[grow];
    }
}

// ---------------- persistent per-group recurrence, MFMA core ----------------
// Panel layout: [buf2][chunk 56][b 16][8 halfs]; chunk c holds k = 8c..8c+7.
// k: 0..63 = x_t | 64..319 = h1 | 320..447 = h2.
__global__ __launch_bounds__(NTHR) void lstm_v4(
    const float* __restrict__ x, const char* __restrict__ wsb,
    float* __restrict__ out)
{
    __shared__ _Float16 pan[2][56 * 16 * 8];   // 2 x 14336 B

    const int tid  = threadIdx.x;
    const int w    = tid >> 6;
    const int lane = tid & 63;
    const int g    = lane >> 4;
    const int b    = lane & 15;
    const int grp  = blockIdx.x;
    const int b0   = grp * Bs;

    const _Float16* wf1g = (const _Float16*)(wsb + OFFB_WF1);
    const _Float16* wf2g = (const _Float16*)(wsb + OFFB_WF2);
    const float*    bf1g = (const float*)(wsb + OFFB_BF1);
    const float*    bf2g = (const float*)(wsb + OFFB_BF2);

    // ---- one-time: weight fragments -> VGPRs ----
    half8 wA1[NT1][NF1];
    half8 wA2[NT2][NF2];
    #pragma unroll
    for (int tt = 0; tt < NT1; ++tt)
        #pragma unroll
        for (int f = 0; f < NF1; ++f)
            wA1[tt][f] = *(const half8*)(wf1g + ((size_t)(((w*4 + tt)*NF1 + f) * 64 + lane)) * 8);
    #pragma unroll
    for (int tt = 0; tt < NT2; ++tt)
        #pragma unroll
        for (int f = 0; f < NF2; ++f)
            wA2[tt][f] = *(const half8*)(wf2g + ((size_t)(((w*2 + tt)*NF2 + f) * 64 + lane)) * 8);

    f32x4 bias1[NT1], bias2[NT2];
    #pragma unroll
    for (int tt = 0; tt < NT1; ++tt)
        bias1[tt] = *(const f32x4*)(bf1g + ((w*4 + tt)*4 + g) * 4);
    #pragma unroll
    for (int tt = 0; tt < NT2; ++tt)
        bias2[tt] = *(const f32x4*)(bf2g + ((w*2 + tt)*4 + g) * 4);

    float c1s[NT1] = {0.f, 0.f, 0.f, 0.f};
    float c2s[NT2] = {0.f, 0.f};

    // zero both panel buffers (h1(-1)=h2(-1)=h2(-2)=0)
    {
        int4* p4 = (int4*)&pan[0][0];
        const int n4 = 2 * 56 * 16 * 8 * 2 / 16;
        for (int i = tid; i < n4; i += NTHR) p4[i] = int4{0, 0, 0, 0};
    }
    __syncthreads();
    // stage x(0) into buf 0
    if (tid < 256) {
        const int sb = tid >> 4, kq = tid & 15;
        const float4 xv = *(const float4*)&x[((size_t)(b0 + sb) * Tt + 0) * NF + kq * 4];
        _Float16* d = &pan[0][(((kq >> 1) * 16) + sb) * 8 + (kq & 1) * 4];
        d[0] = (_Float16)xv.x; d[1] = (_Float16)xv.y;
        d[2] = (_Float16)xv.z; d[3] = (_Float16)xv.w;
    }
    __syncthreads();

    for (int t = 0; t <= Tt; ++t) {
        const int cur = t & 1;
        const _Float16* pc = &pan[cur][0];
        _Float16*       pn = &pan[cur ^ 1][0];

        // ---- layer 1, step t ----
        if (t < Tt) {
            f32x4 acc[NT1] = {};
            #pragma unroll
            for (int f = 0; f < NF1; ++f) {
                const half8 bf = *(const half8*)(pc + (((4*f + g) * 16) + b) * 8);
                #pragma unroll
                for (int tt = 0; tt < NT1; ++tt)
                    acc[tt] = __builtin_amdgcn_mfma_f32_16x16x32_f16(wA1[tt][f], bf, acc[tt], 0, 0, 0);
            }
            #pragma unroll
            for (int tt = 0; tt < NT1; ++tt) {
                const float iv = sigf(acc[tt][0] + bias1[tt][0]);
                const float fv = sigf(acc[tt][1] + bias1[tt][1]);
                const float gv = tanhfast(acc[tt][2] + bias1[tt][2]);
                const float ov = sigf(acc[tt][3] + bias1[tt][3]);
                const float c = fmaf(fv, c1s[tt], iv * gv);
                c1s[tt] = c;
                const float h = ov * tanhfast(c);
                const int u = w*16 + tt*4 + g;                 // global L1 unit
                pn[((8 + (u >> 3)) * 16 + b) * 8 + (u & 7)] = (_Float16)h;
            }
        }
        // ---- layer 2, step s = t-1 ----
        if (t >= 1) {
            const int s = t - 1;
            f32x4 acc[NT2] = {};
            #pragma unroll
            for (int f = 0; f < NF2; ++f) {
                const half8 bf = *(const half8*)(pc + (((8 + 4*f + g) * 16) + b) * 8);
                #pragma unroll
                for (int tt = 0; tt < NT2; ++tt)
                    acc[tt] = __builtin_amdgcn_mfma_f32_16x16x32_f16(wA2[tt][f], bf, acc[tt], 0, 0, 0);
            }
            #pragma unroll
            for (int tt = 0; tt < NT2; ++tt) {
                const float iv = sigf(acc[tt][0] + bias2[tt][0]);
                const float fv = sigf(acc[tt][1] + bias2[tt][1]);
                const float gv = tanhfast(acc[tt][2] + bias2[tt][2]);
                const float ov = sigf(acc[tt][3] + bias2[tt][3]);
                const float c = fmaf(fv, c2s[tt], iv * gv);
                c2s[tt] = c;
                const float h = ov * tanhfast(c);
                const int u2 = w*8 + tt*4 + g;                 // global L2 unit
                pn[((40 + (u2 >> 3)) * 16 + b) * 8 + (u2 & 7)] = (_Float16)h;
                out[((size_t)(b0 + b) * Tt + s) * H2u + u2] = h;
                if (s == Tt - 1)
                    out[(size_t)Bb * Tt * H2u + (size_t)(b0 + b) * H2u + u2] = h;
            }
        }
        // ---- stage x(t+1) into next buffer ----
        if (t + 1 < Tt && tid < 256) {
            const int sb = tid >> 4, kq = tid & 15;
            const float4 xv = *(const float4*)&x[((size_t)(b0 + sb) * Tt + (t + 1)) * NF + kq * 4];
            _Float16* d = &pn[(((kq >> 1) * 16) + sb) * 8 + (kq & 1) * 4];
            d[0] = (_Float16)xv.x; d[1] = (_Float16)xv.y;
            d[2] = (_Float16)xv.z; d[3] = (_Float16)xv.w;
        }
        __syncthreads();
    }
}

extern "C" void kernel_launch(void* const* d_in, const int* in_sizes, int n_in,
                              void* d_out, int out_size, void* d_ws, size_t ws_size,
                              hipStream_t stream) {
    const float* x    = (const float*)d_in[0];
    const float* Wih1 = (const float*)d_in[1];
    const float* Whh1 = (const float*)d_in[2];
    const float* bih1 = (const float*)d_in[3];
    const float* bhh1 = (const float*)d_in[4];
    const float* Wih2 = (const float*)d_in[5];
    const float* Whh2 = (const float*)d_in[6];
    const float* bih2 = (const float*)d_in[7];
    const float* bhh2 = (const float*)d_in[8];
    char*  wsb = (char*)d_ws;
    float* out = (float*)d_out;

    prep4<<<256, 256, 0, stream>>>(Wih1, Whh1, bih1, bhh1,
                                   Wih2, Whh2, bih2, bhh2, wsb);
    lstm_v4<<<NGRP, NTHR, 0, stream>>>(x, wsb, out);
}

// Round 5
// 2018.881 us; speedup vs baseline: 5.5495x; 5.5495x over previous
//
#include <hip/hip_runtime.h>

typedef _Float16 half8 __attribute__((ext_vector_type(8)));
typedef float f32x4 __attribute__((ext_vector_type(4)));
typedef unsigned long long ull;

#define Bb 256
#define Tt 512
#define NF 64
#define H1u 256
#define H2u 128
#define NGRP 16
#define Bs 16
#define NBLK 64
#define NTHR 256

#define NF1 10   // L1 k-frags (K=320)
#define NF2 12   // L2 k-frags (K=384)
#define NT1 4    // L1 16x16 tiles per wave
#define NT2 2    // L2 tiles per wave

// ws byte offsets (frag layout identical to round 4 / prep4, W = slice*4 + wave)
#define OFFB_WF1 0                       // [W16][tt4][f10][lane64] x half8
#define SZB_WF1  (16*4*NF1*64*16)        // 655360
#define OFFB_WF2 (OFFB_WF1+SZB_WF1)      // [W16][tt2][f12][lane64] x half8
#define SZB_WF2  (16*2*NF2*64*16)        // 393216
#define OFFB_BF1 (OFFB_WF2+SZB_WF2)      // [W16][tt4][g4][4] f32
#define SZB_BF1  (16*4*4*4*4)
#define OFFB_BF2 (OFFB_BF1+SZB_BF1)      // [W16][tt2][g4][4] f32
#define SZB_BF2  (16*2*4*4*4)
#define OFFB_PAN (OFFB_BF2+SZB_BF2)      // [par2][grp16][chunk48][b16][8] fp16
#define SZB_PAN  (2*16*48*16*16)         // 393216
#define OFFB_CTR (OFFB_PAN+SZB_PAN)      // 16 counters spaced 64B
#define SZB_CTR  (NGRP*64)

__device__ __forceinline__ float sigf(float x) {
    return 1.0f / (1.0f + __expf(-x));
}
__device__ __forceinline__ float tanhfast(float x) {
    return 2.0f / (1.0f + __expf(-2.0f * x)) - 1.0f;
}

// ---------------- prep: weights -> MFMA A-fragments (fp16), proven in round 4 ----------------
__global__ __launch_bounds__(256) void prep4(
    const float* __restrict__ Wih1, const float* __restrict__ Whh1,
    const float* __restrict__ bih1, const float* __restrict__ bhh1,
    const float* __restrict__ Wih2, const float* __restrict__ Whh2,
    const float* __restrict__ bih2, const float* __restrict__ bhh2,
    char* __restrict__ wsb)
{
    _Float16* wf1 = (_Float16*)(wsb + OFFB_WF1);
    _Float16* wf2 = (_Float16*)(wsb + OFFB_WF2);
    float*    bf1 = (float*)(wsb + OFFB_BF1);
    float*    bf2 = (float*)(wsb + OFFB_BF2);
    const int stride = gridDim.x * blockDim.x;
    const int i0 = blockIdx.x * blockDim.x + threadIdx.x;

    for (int idx = i0; idx < 16*4*NF1*64; idx += stride) {
        const int lane = idx & 63;
        int q = idx >> 6;
        const int f = q % NF1;  q /= NF1;
        const int tt = q & 3;
        const int w  = q >> 2;
        const int r = lane & 15;
        const int unit = w*16 + tt*4 + (r >> 2);
        const int gate = r & 3;
        const int grow = gate * H1u + unit;
        _Float16* dst = wf1 + (size_t)idx * 8;
        #pragma unroll
        for (int e = 0; e < 8; ++e) {
            const int k = f*32 + (lane >> 4)*8 + e;
            const float v = (k < NF) ? Wih1[grow*NF + k]
                                     : Whh1[grow*H1u + (k - NF)];
            dst[e] = (_Float16)v;
        }
    }
    for (int idx = i0; idx < 16*2*NF2*64; idx += stride) {
        const int lane = idx & 63;
        int q = idx >> 6;
        const int f = q % NF2;  q /= NF2;
        const int tt = q & 1;
        const int w  = q >> 1;
        const int r = lane & 15;
        const int unit = w*8 + tt*4 + (r >> 2);
        const int gate = r & 3;
        const int grow = gate * H2u + unit;
        _Float16* dst = wf2 + (size_t)idx * 8;
        #pragma unroll
        for (int e = 0; e < 8; ++e) {
            const int k = f*32 + (lane >> 4)*8 + e;
            const float v = (k < H1u) ? Wih2[grow*H1u + k]
                                      : Whh2[grow*H2u + (k - H1u)];
            dst[e] = (_Float16)v;
        }
    }
    for (int idx = i0; idx < 16*4*4*4; idx += stride) {
        const int reg = idx & 3, lg = (idx >> 2) & 3;
        const int tt = (idx >> 4) & 3, w = idx >> 6;
        const int unit = w*16 + tt*4 + lg;
        const int grow = reg * H1u + unit;
        bf1[idx] = bih1[grow] + bhh1[grow];
    }
    for (int idx = i0; idx < 16*2*4*4; idx += stride) {
        const int reg = idx & 3, lg = (idx >> 2) & 3;
        const int tt = (idx >> 4) & 1, w = idx >> 5;
        const int unit = w*8 + tt*4 + lg;
        const int grow = reg * H2u + unit;
        bf2[idx] = bih2[grow] + bhh2[grow];
    }
}

// ---------------- persistent recurrence: 64 blocks = 16 groups x 4 row-slices ----------------
__global__ __launch_bounds__(NTHR, 1) void lstm_v5(
    const float* __restrict__ x, const char* __restrict__ wsb,
    ull* pan, unsigned* ctrs, float* __restrict__ out)
{
    const int tid   = threadIdx.x;
    const int w     = tid >> 6;
    const int lane  = tid & 63;
    const int g     = lane >> 4;          // k-quarter within frag / unit-in-tile
    const int b     = lane & 15;          // batch within group
    const int grp   = blockIdx.x & 15;
    const int slice = blockIdx.x >> 4;
    const int W     = slice * 4 + w;      // global wave-slot 0..15
    const int b0    = grp * Bs;

    const _Float16* wf1g = (const _Float16*)(wsb + OFFB_WF1);
    const _Float16* wf2g = (const _Float16*)(wsb + OFFB_WF2);
    const float*    bf1g = (const float*)(wsb + OFFB_BF1);
    const float*    bf2g = (const float*)(wsb + OFFB_BF2);

    // ---- one-time: weight fragments -> VGPRs (static indices, fully unrolled) ----
    half8 wA1[NT1][NF1];
    half8 wA2[NT2][NF2];
    #pragma unroll
    for (int tt = 0; tt < NT1; ++tt)
        #pragma unroll
        for (int f = 0; f < NF1; ++f)
            wA1[tt][f] = *(const half8*)(wf1g + ((size_t)(((W*4 + tt)*NF1 + f) * 64 + lane)) * 8);
    #pragma unroll
    for (int tt = 0; tt < NT2; ++tt)
        #pragma unroll
        for (int f = 0; f < NF2; ++f)
            wA2[tt][f] = *(const half8*)(wf2g + ((size_t)(((W*2 + tt)*NF2 + f) * 64 + lane)) * 8);

    f32x4 bias1[NT1], bias2[NT2];
    #pragma unroll
    for (int tt = 0; tt < NT1; ++tt)
        bias1[tt] = *(const f32x4*)(bf1g + ((W*4 + tt)*4 + g) * 4);
    #pragma unroll
    for (int tt = 0; tt < NT2; ++tt)
        bias2[tt] = *(const f32x4*)(bf2g + ((W*2 + tt)*4 + g) * 4);

    float c1s[NT1] = {0.f, 0.f, 0.f, 0.f};
    float c2s[NT2] = {0.f, 0.f};

    unsigned* ctr = ctrs + grp * 16;          // 64B-spaced
    unsigned short* pan16 = (unsigned short*)pan;

    for (int t = 0; t <= Tt; ++t) {
        const int parW1 = t & 1;              // h1(t) write parity
        const int parR1 = (t + 1) & 1;        // h1(t-1) read parity
        const int parW2 = (t + 1) & 1;        // h2(t-1) write parity
        const int parR2 = t & 1;              // h2(t-2) read parity

        const size_t base1 = (size_t)(parR1 * 16 + grp) * 1536;        // ull idx
        const size_t base2 = (size_t)(parR2 * 16 + grp) * 1536 + 1024; // + chunk32*32

        half8 bf1f[NF1];
        half8 bf2f[NF2];

        // ---- B-fragment loads ----
        if (t < Tt) {
            #pragma unroll
            for (int f = 0; f < 2; ++f) {     // x(t), fp32 -> fp16
                const float* xp = x + (((size_t)(b0 + b)) * Tt + t) * NF + f * 32 + g * 8;
                const float4 lo = *(const float4*)xp;
                const float4 hi = *(const float4*)(xp + 4);
                half8 v;
                v[0] = (_Float16)lo.x; v[1] = (_Float16)lo.y;
                v[2] = (_Float16)lo.z; v[3] = (_Float16)lo.w;
                v[4] = (_Float16)hi.x; v[5] = (_Float16)hi.y;
                v[6] = (_Float16)hi.z; v[7] = (_Float16)hi.w;
                bf1f[f] = v;
            }
            #pragma unroll
            for (int i = 0; i < 8; ++i) {     // h1(t-1), coherent
                const size_t a = base1 + (size_t)(4*i + g) * 32 + b * 2;
                union { ull q[2]; half8 h; } u;
                u.q[0] = __hip_atomic_load(pan + a,     __ATOMIC_RELAXED, __HIP_MEMORY_SCOPE_AGENT);
                u.q[1] = __hip_atomic_load(pan + a + 1, __ATOMIC_RELAXED, __HIP_MEMORY_SCOPE_AGENT);
                bf1f[2 + i] = u.h;
            }
        }
        if (t >= 1) {
            if (t < Tt) {
                #pragma unroll
                for (int f = 0; f < 8; ++f) bf2f[f] = bf1f[2 + f];   // same h1(t-1)
            } else {
                #pragma unroll
                for (int f = 0; f < 8; ++f) {
                    const size_t a = base1 + (size_t)(4*f + g) * 32 + b * 2;
                    union { ull q[2]; half8 h; } u;
                    u.q[0] = __hip_atomic_load(pan + a,     __ATOMIC_RELAXED, __HIP_MEMORY_SCOPE_AGENT);
                    u.q[1] = __hip_atomic_load(pan + a + 1, __ATOMIC_RELAXED, __HIP_MEMORY_SCOPE_AGENT);
                    bf2f[f] = u.h;
                }
            }
            #pragma unroll
            for (int f = 0; f < 4; ++f) {     // h2(t-2)
                const size_t a = base2 + (size_t)(4*f + g) * 32 + b * 2;
                union { ull q[2]; half8 h; } u;
                u.q[0] = __hip_atomic_load(pan + a,     __ATOMIC_RELAXED, __HIP_MEMORY_SCOPE_AGENT);
                u.q[1] = __hip_atomic_load(pan + a + 1, __ATOMIC_RELAXED, __HIP_MEMORY_SCOPE_AGENT);
                bf2f[8 + f] = u.h;
            }
        }

        // ---- layer 1, step t ----
        if (t < Tt) {
            f32x4 acc[NT1] = {};
            #pragma unroll
            for (int f = 0; f < NF1; ++f)
                #pragma unroll
                for (int tt = 0; tt < NT1; ++tt)
                    acc[tt] = __builtin_amdgcn_mfma_f32_16x16x32_f16(wA1[tt][f], bf1f[f], acc[tt], 0, 0, 0);
            #pragma unroll
            for (int tt = 0; tt < NT1; ++tt) {
                const float iv = sigf(acc[tt][0] + bias1[tt][0]);
                const float fv = sigf(acc[tt][1] + bias1[tt][1]);
                const float gv = tanhfast(acc[tt][2] + bias1[tt][2]);
                const float ov = sigf(acc[tt][3] + bias1[tt][3]);
                const float c = fmaf(fv, c1s[tt], iv * gv);
                c1s[tt] = c;
                const float h = ov * tanhfast(c);
                const int u = W * 16 + tt * 4 + g;
                union { _Float16 f; unsigned short s; } hc;
                hc.f = (_Float16)h;
                const size_t si = ((size_t)(parW1 * 16 + grp) * 48 + (u >> 3)) * 128 + b * 8 + (u & 7);
                __hip_atomic_store(pan16 + si, hc.s, __ATOMIC_RELAXED, __HIP_MEMORY_SCOPE_AGENT);
            }
        }
        // ---- layer 2, step s = t-1 ----
        if (t >= 1) {
            const int s = t - 1;
            f32x4 acc[NT2] = {};
            #pragma unroll
            for (int f = 0; f < NF2; ++f)
                #pragma unroll
                for (int tt = 0; tt < NT2; ++tt)
                    acc[tt] = __builtin_amdgcn_mfma_f32_16x16x32_f16(wA2[tt][f], bf2f[f], acc[tt], 0, 0, 0);
            #pragma unroll
            for (int tt = 0; tt < NT2; ++tt) {
                const float iv = sigf(acc[tt][0] + bias2[tt][0]);
                const float fv = sigf(acc[tt][1] + bias2[tt][1]);
                const float gv = tanhfast(acc[tt][2] + bias2[tt][2]);
                const float ov = sigf(acc[tt][3] + bias2[tt][3]);
                const float c = fmaf(fv, c2s[tt], iv * gv);
                c2s[tt] = c;
                const float h = ov * tanhfast(c);
                const int u2 = W * 8 + tt * 4 + g;
                union { _Float16 f; unsigned short s; } hc;
                hc.f = (_Float16)h;
                const size_t si = ((size_t)(parW2 * 16 + grp) * 48 + 32 + (u2 >> 3)) * 128 + b * 8 + (u2 & 7);
                __hip_atomic_store(pan16 + si, hc.s, __ATOMIC_RELAXED, __HIP_MEMORY_SCOPE_AGENT);
                out[((size_t)(b0 + b) * Tt + s) * H2u + u2] = h;
                if (s == Tt - 1)
                    out[(size_t)Bb * Tt * H2u + (size_t)(b0 + b) * H2u + u2] = h;
            }
        }
        // ---- group barrier: syncthreads drains vmcnt (stores at coherence point),
        //      then relaxed counter; readers' relaxed loads fetch from coherence point ----
        if (t < Tt) {
            __syncthreads();
            if (tid == 0) {
                __hip_atomic_fetch_add(ctr, 1u, __ATOMIC_RELAXED, __HIP_MEMORY_SCOPE_AGENT);
                const unsigned tgt = 4u * (unsigned)(t + 1);
                while (__hip_atomic_load(ctr, __ATOMIC_RELAXED, __HIP_MEMORY_SCOPE_AGENT) < tgt)
                    __builtin_amdgcn_s_sleep(2);
            }
            __syncthreads();
        }
    }
}

extern "C" void kernel_launch(void* const* d_in, const int* in_sizes, int n_in,
                              void* d_out, int out_size, void* d_ws, size_t ws_size,
                              hipStream_t stream) {
    const float* x    = (const float*)d_in[0];
    const float* Wih1 = (const float*)d_in[1];
    const float* Whh1 = (const float*)d_in[2];
    const float* bih1 = (const float*)d_in[3];
    const float* bhh1 = (const float*)d_in[4];
    const float* Wih2 = (const float*)d_in[5];
    const float* Whh2 = (const float*)d_in[6];
    const float* bih2 = (const float*)d_in[7];
    const float* bhh2 = (const float*)d_in[8];
    char*  wsb = (char*)d_ws;
    float* out = (float*)d_out;

    prep4<<<256, 256, 0, stream>>>(Wih1, Whh1, bih1, bhh1,
                                   Wih2, Whh2, bih2, bhh2, wsb);
    // zero h panels + counters every launch (deterministic; counters monotonic per run)
    hipMemsetAsync((void*)(wsb + OFFB_PAN), 0, SZB_PAN + SZB_CTR, stream);
    lstm_v5<<<NBLK, NTHR, 0, stream>>>(
        x, wsb, (ull*)(wsb + OFFB_PAN), (unsigned*)(wsb + OFFB_CTR), out);
}